// Round 9
// baseline (310.383 us; speedup 1.0000x reference)
//
#include <hip/hip_runtime.h>
#include <hip/hip_bf16.h>

typedef __bf16 bf16;
typedef __bf16 bf16x2 __attribute__((ext_vector_type(2)));
typedef __bf16 bf16x4 __attribute__((ext_vector_type(4)));
typedef __bf16 bf16x8 __attribute__((ext_vector_type(8)));
typedef float f32x4 __attribute__((ext_vector_type(4)));
typedef float f32x16 __attribute__((ext_vector_type(16)));

#define DIM 1536
#define NH 12
#define HD 128
#define SEQ 1560
#define KV 9360
#define KVP 9408      // padded to 147*64 so staging never needs clamps
#define SINK 1560
#define NEWBASE 7800  // k_cat rows [7800,9360) are the new tokens
// logits computed in log2 domain: Q pre-scaled by HD^-0.5 * log2(e)
#define QSCALE_L2E (0.08838834764831845f * 1.4426950408889634f)
#define NSPLIT 3
#define CHUNK 3136    // 49 tiles; 3*3136 = 9408 = KVP exactly
#define NT 49
#define QBLK 128
#define NQT 13        // ceil(1560/128)

__device__ __forceinline__ void gl_lds16(const void* g, void* l) {
  __builtin_amdgcn_global_load_lds(
      (const __attribute__((address_space(1))) unsigned int*)g,
      (__attribute__((address_space(3))) unsigned int*)l, 16, 0, 0);
}

__device__ __forceinline__ f32x16 mfma32(bf16x8 a, bf16x8 b, f32x16 c) {
  return __builtin_amdgcn_mfma_f32_32x32x16_bf16(a, b, c, 0, 0, 0);
}

// ---------------- fused cast f32 -> bf16 (x + 4 weights) ----------------
struct CastBatch {
  const float* src[5];
  bf16* dst[5];
  int n[5];
};
__global__ __launch_bounds__(256) void castall(CastBatch cb) {
  const float* src = cb.src[blockIdx.y];
  bf16* dst = cb.dst[blockIdx.y];
  int n = cb.n[blockIdx.y];
  int i = (blockIdx.x * 256 + threadIdx.x) * 8;
  if (i < n) {
    float4 a = *(const float4*)(src + i);
    float4 b = *(const float4*)(src + i + 4);
    bf16x8 o;
    o[0] = (bf16)a.x; o[1] = (bf16)a.y; o[2] = (bf16)a.z; o[3] = (bf16)a.w;
    o[4] = (bf16)b.x; o[5] = (bf16)b.y; o[6] = (bf16)b.z; o[7] = (bf16)b.w;
    *(bf16x8*)(dst + i) = o;
  }
}

// ---- zero the KVP padding rows/cols so no ws read is ever uninitialized ----
__global__ __launch_bounds__(256) void clear_pad(bf16* __restrict__ Kcat,
                                                 bf16* __restrict__ Vt) {
  int h = blockIdx.y;
  int i = blockIdx.x * 256 + threadIdx.x;  // [0, 6144)
  if (i < (KVP - KV) * HD) {
    int r = KV + i / HD, d = i % HD;
    Kcat[((size_t)h * KVP + r) * HD + d] = (bf16)0.f;
    int dv = i / (KVP - KV), j = KV + i % (KVP - KV);
    Vt[((size_t)h * HD + dv) * KVP + j] = (bf16)0.f;
  }
}

// ---------------- GEMM: C[M,N] = A[M,K] * B[N,K]^T + bias, f32 out ----------------
struct GemmBatch {
  const bf16* B[3];
  const float* bias[3];
  float* C[3];
};

#define BM 128
#define BN 128
#define BK 32

__global__ __launch_bounds__(256, 2) void gemm_bt(const bf16* __restrict__ A,
                                                  GemmBatch gb, int M) {
  const bf16* Bw = gb.B[blockIdx.z];
  const float* bias = gb.bias[blockIdx.z];
  float* C = gb.C[blockIdx.z];
  int bm = blockIdx.x * BM;
  int bn = blockIdx.y * BN;

  __shared__ bf16 Alds[2][BM][BK];
  __shared__ bf16 Blds[2][BN][BK];

  int t = threadIdx.x;
  int lane = t & 63;
  int wave = t >> 6;
  int wr = wave >> 1, wc = wave & 1;
  int fr = lane & 15;
  int fo = (lane >> 4) * 8;

  f32x4 acc[4][4] = {};

  const int NK = DIM / BK;  // 48
  int colA = (lane & 3) * 8;
  int lrow = lane >> 2;

#define STAGEG(buf, k0)                                                     \
  {                                                                         \
    _Pragma("unroll") for (int p = 0; p < 2; ++p) {                         \
      int rbase = wave * 16 + p * 64;                                       \
      int ga = bm + rbase + lrow;                                           \
      if (ga > M - 1) ga = M - 1;                                           \
      gl_lds16(A + (size_t)ga * DIM + (k0) + colA, &Alds[buf][rbase][0]);   \
      int gbv = bn + rbase + lrow;                                          \
      gl_lds16(Bw + (size_t)gbv * DIM + (k0) + colA, &Blds[buf][rbase][0]); \
    }                                                                       \
  }

  STAGEG(0, 0);
  int cur = 0;
  for (int ks = 0; ks < NK; ++ks) {
    __syncthreads();  // drains vmcnt -> buf[cur] ready
    if (ks + 1 < NK) STAGEG(cur ^ 1, (ks + 1) * BK);
    bf16x8 af[4], bfv[4];
#pragma unroll
    for (int i = 0; i < 4; ++i)
      af[i] = *(const bf16x8*)&Alds[cur][wr * 64 + i * 16 + fr][fo];
#pragma unroll
    for (int j = 0; j < 4; ++j)
      bfv[j] = *(const bf16x8*)&Blds[cur][wc * 64 + j * 16 + fr][fo];
#pragma unroll
    for (int i = 0; i < 4; ++i)
#pragma unroll
      for (int j = 0; j < 4; ++j)
        acc[i][j] = __builtin_amdgcn_mfma_f32_16x16x32_bf16(af[i], bfv[j],
                                                            acc[i][j], 0, 0, 0);
    cur ^= 1;
  }
#undef STAGEG

  int g4 = (lane >> 4) * 4;
#pragma unroll
  for (int i = 0; i < 4; ++i) {
    int mbase = bm + wr * 64 + i * 16 + g4;
#pragma unroll
    for (int j = 0; j < 4; ++j) {
      int col = bn + wc * 64 + j * 16 + fr;
      float bv = bias[col];
#pragma unroll
      for (int r = 0; r < 4; ++r) {
        int m = mbase + r;
        if (m < M) C[(size_t)m * DIM + col] = acc[i][j][r] + bv;
      }
    }
  }
}

// ---------------- RMSNorm + RoPE for q,k ----------------
__global__ __launch_bounds__(256) void norm_rope(
    const float* __restrict__ qraw, const float* __restrict__ kraw,
    const float* __restrict__ nqw, const float* __restrict__ nkw,
    const float* __restrict__ fcos, const float* __restrict__ fsin,
    bf16* __restrict__ Qh, bf16* __restrict__ Kcat) {
  int tok = blockIdx.x;
  int tid = threadIdx.x;
  const float* qr = qraw + (size_t)tok * DIM;
  const float* kr = kraw + (size_t)tok * DIM;
  float sq = 0.f, sk = 0.f;
  for (int c = tid; c < DIM; c += 256) {
    float a = qr[c];
    sq += a * a;
    float b = kr[c];
    sk += b * b;
  }
#pragma unroll
  for (int off = 32; off; off >>= 1) {
    sq += __shfl_down(sq, off);
    sk += __shfl_down(sk, off);
  }
  __shared__ float red[2][4];
  int w = tid >> 6;
  if ((tid & 63) == 0) {
    red[0][w] = sq;
    red[1][w] = sk;
  }
  __syncthreads();
  sq = red[0][0] + red[0][1] + red[0][2] + red[0][3];
  sk = red[1][0] + red[1][1] + red[1][2] + red[1][3];
  float rsq = rsqrtf(sq * (1.0f / DIM) + 1e-6f);
  float rsk = rsqrtf(sk * (1.0f / DIM) + 1e-6f);

  int hrow = tok / 52, wrow = tok % 52;
  for (int p = tid; p < NH * 64; p += 256) {
    int n = p >> 6, i = p & 63;
    int trow = (i < 22) ? 6 : (i < 43 ? hrow : wrow);
    float cs = fcos[trow * 64 + i];
    float sn = fsin[trow * 64 + i];
    int c = n * HD + 2 * i;
    float xr = qr[c] * rsq * nqw[c];
    float xi = qr[c + 1] * rsq * nqw[c + 1];
    bf16x2 qo;
    qo[0] = (bf16)((xr * cs - xi * sn) * QSCALE_L2E);
    qo[1] = (bf16)((xr * sn + xi * cs) * QSCALE_L2E);
    *(bf16x2*)(Qh + ((size_t)n * SEQ + tok) * HD + 2 * i) = qo;
    float yr = kr[c] * rsk * nkw[c];
    float yi = kr[c + 1] * rsk * nkw[c + 1];
    bf16x2 ko;
    ko[0] = (bf16)(yr * cs - yi * sn);
    ko[1] = (bf16)(yr * sn + yi * cs);
    *(bf16x2*)(Kcat + ((size_t)n * KVP + NEWBASE + tok) * HD + 2 * i) = ko;
  }
}

// ---------------- gather cache_k rows into K_cat ----------------
__global__ __launch_bounds__(256) void build_kcat(const float* __restrict__ cache_k,
                                                  bf16* __restrict__ Kcat) {
  int j = blockIdx.x;  // 0..7799
  int src = j < SINK ? j : j + SINK;
  const float* sp = cache_k + (size_t)src * DIM;
  for (int c4 = threadIdx.x; c4 < DIM / 4; c4 += 256) {
    float4 v = *(const float4*)(sp + c4 * 4);
    int c = c4 * 4;
    int n = c >> 7, d = c & 127;
    bf16x4 o;
    o[0] = (bf16)v.x; o[1] = (bf16)v.y; o[2] = (bf16)v.z; o[3] = (bf16)v.w;
    *(bf16x4*)(Kcat + ((size_t)n * KVP + j) * HD + d) = o;
  }
}

// ---------------- build transposed V: Vt[h][d][j] ----------------
__global__ __launch_bounds__(256) void build_vt(const float* __restrict__ cache_v,
                                                const float* __restrict__ vraw,
                                                bf16* __restrict__ Vt) {
  int h = blockIdx.y;
  int j0 = blockIdx.x * 64;
  __shared__ bf16 T[128][72];
  int tid = threadIdx.x;
  for (int idx = tid; idx < 64 * 32; idx += 256) {
    int jl = idx >> 5, s = idx & 31;
    int j = j0 + jl;
    if (j >= KV) continue;
    const float* sp;
    if (j < NEWBASE) {
      int srcj = j < SINK ? j : j + SINK;
      sp = cache_v + (size_t)srcj * DIM + h * HD;
    } else {
      sp = vraw + (size_t)(j - NEWBASE) * DIM + h * HD;
    }
    float4 v = *(const float4*)(sp + s * 4);
    T[s * 4 + 0][jl] = (bf16)v.x;
    T[s * 4 + 1][jl] = (bf16)v.y;
    T[s * 4 + 2][jl] = (bf16)v.z;
    T[s * 4 + 3][jl] = (bf16)v.w;
  }
  __syncthreads();
  for (int idx = tid; idx < 128 * 16; idx += 256) {
    int d = idx >> 4, g = idx & 15;
    int j = j0 + g * 4;
    if (j + 4 > KV) continue;
    bf16x4 o;
    o[0] = T[d][4 * g];
    o[1] = T[d][4 * g + 1];
    o[2] = T[d][4 * g + 2];
    o[3] = T[d][4 * g + 3];
    *(bf16x4*)(Vt + ((size_t)h * HD + d) * KVP + j) = o;
  }
}

// ---- flash attention: 32x32 MFMA, swapped QK^T, in-register P (no Plds) ----
__global__ __launch_bounds__(256, 2) void attn_split(const bf16* __restrict__ Qh,
                                                     const bf16* __restrict__ Kcat,
                                                     const bf16* __restrict__ Vtg,
                                                     float* __restrict__ Opart,
                                                     float* __restrict__ MLpart) {
  // bijective XCD swizzle (m204): NB = 13*12*3 = 468, q=58, r=4
  int orig = blockIdx.x;
  int xcd = orig & 7, jj = orig >> 3;
  int wgid = (xcd < 4 ? xcd * 59 : 236 + (xcd - 4) * 58) + jj;
  int qt = wgid % NQT;
  int h = (wgid / NQT) % NH;
  int sp = wgid / (NQT * NH);
  int q0 = qt * QBLK;
  int c0 = sp * CHUNK;

  int t = threadIdx.x, lane = t & 63, w = t >> 6;
  int ql = lane & 31, hi = lane >> 5;

  __shared__ __align__(16) bf16 Klds[2][64 * 128];   // 2 x 16 KB, 4-bit XOR swizzle
  __shared__ __align__(16) bf16 Vlds[2][128 * 64];   // 2 x 16 KB, 3-bit XOR swizzle

  // Q fragments (B-operand of 32x32x16): lane holds Q[q=ql][ks*16 + hi*8 + j]
  int qrow = q0 + w * 32 + ql;
  int qcl = qrow < SEQ ? qrow : SEQ - 1;
  const bf16* Qp = Qh + ((size_t)h * SEQ + qcl) * HD + hi * 8;
  bf16x8 qreg[8];
#pragma unroll
  for (int ks = 0; ks < 8; ++ks) qreg[ks] = *(const bf16x8*)(Qp + ks * 16);

  // staging: linear LDS dest (gl_lds), pre-swizzled global source
  int kadd[4], vadd[4];
#pragma unroll
  for (int p = 0; p < 4; ++p) {
    int rK = (4 * w + p) * 4 + (lane >> 4);
    int cK = (lane & 15) ^ (rK & 15);
    kadd[p] = rK * HD + cK * 8;
    int dV = (4 * w + p) * 8 + (lane >> 3);
    int cV = (lane & 7) ^ (dV & 7);
    vadd[p] = dV * KVP + cV * 8;
  }

  // swizzled LDS read offsets
  int koff[2][8];
#pragma unroll
  for (int kb = 0; kb < 2; ++kb)
#pragma unroll
    for (int ks = 0; ks < 8; ++ks)
      koff[kb][ks] = (kb * 32 + ql) * 256 + (((ks * 2 + hi) ^ (ql & 15)) * 16);
  int voff[4][4];
#pragma unroll
  for (int db = 0; db < 4; ++db)
#pragma unroll
    for (int ks = 0; ks < 4; ++ks)
      voff[db][ks] = (db * 32 + ql) * 128 + (((ks * 2 + hi) ^ (ql & 7)) * 16);

  const bf16* Khp = Kcat + (size_t)h * KVP * HD;
  const bf16* Vhp = Vtg + (size_t)h * HD * KVP;

  f32x16 oacc[4] = {};
  float m_q = -1e38f, l_q = 0.f;

#define STAGE(buf, j0)                                                        \
  {                                                                           \
    const bf16* Ks = Khp + (size_t)(j0)*HD;                                   \
    const bf16* Vs = Vhp + (j0);                                              \
    _Pragma("unroll") for (int p = 0; p < 4; ++p) {                           \
      gl_lds16(Ks + kadd[p], (char*)&Klds[buf][0] + w * 4096 + p * 1024);     \
      gl_lds16(Vs + vadd[p], (char*)&Vlds[buf][0] + w * 4096 + p * 1024);     \
    }                                                                         \
  }

  STAGE(0, c0);
  __syncthreads();  // drain -> buf0 ready
  int cur = 0;

  for (int ti = 0; ti < NT; ++ti) {
    int j0 = c0 + ti * 64;
    if (ti + 1 < NT) STAGE(cur ^ 1, j0 + 64);  // prefetch overlaps compute

    const char* Kc = (const char*)&Klds[cur][0];
    const char* Vc = (const char*)&Vlds[cur][0];

    // S^T[k][q] = K · Q^T (log2 domain); lane holds q=ql,
    // k = kb*32 + (reg&3) + 8*(reg>>2) + 4*hi
    f32x16 s0 = {}, s1 = {};
    __builtin_amdgcn_s_setprio(1);
#pragma unroll
    for (int ks = 0; ks < 8; ++ks) {
      s0 = mfma32(*(const bf16x8*)(Kc + koff[0][ks]), qreg[ks], s0);
      s1 = mfma32(*(const bf16x8*)(Kc + koff[1][ks]), qreg[ks], s1);
    }
    __builtin_amdgcn_s_setprio(0);

    if (j0 + 64 > KV) {
#pragma unroll
      for (int reg = 0; reg < 16; ++reg) {
        int kk = (reg & 3) + 8 * (reg >> 2) + 4 * hi;
        if (j0 + kk >= KV) s0[reg] = -1e38f;
        if (j0 + 32 + kk >= KV) s1[reg] = -1e38f;
      }
    }

    // lane-local tree max over 32 scores + partner merge
    f32x16 mm;
#pragma unroll
    for (int r = 0; r < 16; ++r) mm[r] = fmaxf(s0[r], s1[r]);
    float m8[8];
#pragma unroll
    for (int r = 0; r < 8; ++r) m8[r] = fmaxf(mm[r], mm[r + 8]);
    float mx = fmaxf(fmaxf(fmaxf(m8[0], m8[4]), fmaxf(m8[1], m8[5])),
                     fmaxf(fmaxf(m8[2], m8[6]), fmaxf(m8[3], m8[7])));
    mx = fmaxf(mx, __shfl_xor(mx, 32));

    // defer-max: rescale only when max grows by > 8 (log2 units)
    if (__any(mx - m_q > 8.f)) {
      float mnew = fmaxf(m_q, mx);
      float corr = exp2f(m_q - mnew);
      m_q = mnew;
      l_q *= corr;
#pragma unroll
      for (int reg = 0; reg < 16; ++reg) {
        int qsrc = (reg & 3) + 8 * (reg >> 2) + 4 * hi;
        float c = __shfl(corr, qsrc);
#pragma unroll
        for (int db = 0; db < 4; ++db) oacc[db][reg] *= c;
      }
    }

    // P = exp2(s - m) in-register, tree sum
#pragma unroll
    for (int r = 0; r < 16; ++r) {
      s0[r] = exp2f(s0[r] - m_q);
      s1[r] = exp2f(s1[r] - m_q);
    }
    f32x16 ss;
#pragma unroll
    for (int r = 0; r < 16; ++r) ss[r] = s0[r] + s1[r];
    float t8[8];
#pragma unroll
    for (int r = 0; r < 8; ++r) t8[r] = ss[r] + ss[r + 8];
    float sum = ((t8[0] + t8[4]) + (t8[1] + t8[5])) +
                ((t8[2] + t8[6]) + (t8[3] + t8[7]));
    sum += __shfl_xor(sum, 32);
    l_q += sum;

    // P -> A-fragments: bf16 pack (compiler emits cvt_pk) + shfl_xor(32)
    // redistribution + per-half select. No inline asm.
    bf16x8 pa[4];
#pragma unroll
    for (int ks = 0; ks < 4; ++ks) {
      const f32x16& S = (ks < 2) ? s0 : s1;
      const int r0 = (ks & 1) * 8;
      bf16x2 p0, p1, p2, p3;
      p0[0] = (bf16)S[r0 + 0]; p0[1] = (bf16)S[r0 + 1];
      p1[0] = (bf16)S[r0 + 2]; p1[1] = (bf16)S[r0 + 3];
      p2[0] = (bf16)S[r0 + 4]; p2[1] = (bf16)S[r0 + 5];
      p3[0] = (bf16)S[r0 + 6]; p3[1] = (bf16)S[r0 + 7];
      int x0 = __builtin_bit_cast(int, p0);
      int x1 = __builtin_bit_cast(int, p1);
      int y0 = __builtin_bit_cast(int, p2);
      int y1 = __builtin_bit_cast(int, p3);
      int sx0 = __shfl_xor(x0, 32);
      int sx1 = __shfl_xor(x1, 32);
      int sy0 = __shfl_xor(y0, 32);
      int sy1 = __shfl_xor(y1, 32);
      int4 tmp;
      tmp.x = hi ? sy0 : x0;
      tmp.y = hi ? sy1 : x1;
      tmp.z = hi ? y0 : sx0;
      tmp.w = hi ? y1 : sx1;
      pa[ks] = __builtin_bit_cast(bf16x8, tmp);
    }

    // O[q][d] += P · V
    __builtin_amdgcn_s_setprio(1);
#pragma unroll
    for (int db = 0; db < 4; ++db)
#pragma unroll
      for (int ks = 0; ks < 4; ++ks)
        oacc[db] = mfma32(pa[ks], *(const bf16x8*)(Vc + voff[db][ks]), oacc[db]);
    __builtin_amdgcn_s_setprio(0);

    __syncthreads();  // drains next-tile loads + WAR on cur
    cur ^= 1;
  }
#undef STAGE

  // store unnormalized partials: lane holds O[q=...reg...][d=db*32+ql]
  float* Oh = Opart + ((size_t)sp * NH + h) * SEQ * HD;
  float* MLh = MLpart + ((size_t)sp * NH + h) * SEQ * 2;
#pragma unroll
  for (int reg = 0; reg < 16; ++reg) {
    int q = q0 + w * 32 + (reg & 3) + 8 * (reg >> 2) + 4 * hi;
    if (q >= SEQ) continue;
#pragma unroll
    for (int db = 0; db < 4; ++db)
      Oh[(size_t)q * HD + db * 32 + ql] = oacc[db][reg];
  }
  if (lane < 32) {
    int q = q0 + w * 32 + ql;
    if (q < SEQ) {
      MLh[q * 2 + 0] = m_q;
      MLh[q * 2 + 1] = l_q;
    }
  }
}

// ---------------- merge split partials (log2-domain m) ----------------
__global__ __launch_bounds__(256) void attn_merge(const float* __restrict__ Opart,
                                                  const float* __restrict__ MLpart,
                                                  bf16* __restrict__ Aout) {
  int idx = blockIdx.x * 2 + (threadIdx.x >> 7);
  if (idx >= NH * SEQ) return;
  int d = threadIdx.x & 127;
  int h = idx / SEQ, q = idx % SEQ;
  float m[NSPLIT];
  float M = -1e38f;
#pragma unroll
  for (int s = 0; s < NSPLIT; ++s) {
    m[s] = MLpart[(((size_t)s * NH + h) * SEQ + q) * 2];
    M = fmaxf(M, m[s]);
  }
  float L = 0.f, o = 0.f;
#pragma unroll
  for (int s = 0; s < NSPLIT; ++s) {
    float wgt = exp2f(m[s] - M);
    L += MLpart[(((size_t)s * NH + h) * SEQ + q) * 2 + 1] * wgt;
    o += Opart[((((size_t)s * NH + h) * SEQ + q)) * HD + d] * wgt;
  }
  Aout[(size_t)q * DIM + h * HD + d] = (bf16)(o / L);
}

// ---------------- host ----------------
extern "C" void kernel_launch(void* const* d_in, const int* in_sizes, int n_in,
                              void* d_out, int out_size, void* d_ws, size_t ws_size,
                              hipStream_t stream) {
  const float* x = (const float*)d_in[0];
  const float* Wq = (const float*)d_in[1];
  const float* bq = (const float*)d_in[2];
  const float* Wk = (const float*)d_in[3];
  const float* bk = (const float*)d_in[4];
  const float* Wv = (const float*)d_in[5];
  const float* bv = (const float*)d_in[6];
  const float* Wo = (const float*)d_in[7];
  const float* bo = (const float*)d_in[8];
  const float* nqw = (const float*)d_in[9];
  const float* nkw = (const float*)d_in[10];
  const float* cache_k = (const float*)d_in[11];
  const float* cache_v = (const float*)d_in[12];
  const float* fcos = (const float*)d_in[13];
  const float* fsin = (const float*)d_in[14];
  float* out = (float*)d_out;

  char* ws = (char*)d_ws;
  size_t off = 0;
  auto alloc = [&](size_t bytes) {
    char* p = ws + off;
    off += (bytes + 255) & ~(size_t)255;
    return p;
  };
  const int XN = SEQ * DIM;       // 2,396,160
  const int WN = DIM * DIM;       // 2,359,296
  bf16* xb = (bf16*)alloc((size_t)XN * 2);
  bf16* Wqb = (bf16*)alloc((size_t)WN * 2);
  bf16* Wkb = (bf16*)alloc((size_t)WN * 2);
  bf16* Wvb = (bf16*)alloc((size_t)WN * 2);
  bf16* Wob = (bf16*)alloc((size_t)WN * 2);
  bf16* QhB = (bf16*)alloc((size_t)NH * SEQ * HD * 2);
  bf16* Kcat = (bf16*)alloc((size_t)NH * KVP * HD * 2);
  bf16* Vt = (bf16*)alloc((size_t)NH * HD * KVP * 2);
  bf16* Aout = (bf16*)alloc((size_t)XN * 2);
  float* MLpart = (float*)alloc((size_t)NSPLIT * NH * SEQ * 2 * 4);
  // Opart (written by attn_split) overlays qraw/kraw/vraw (dead after build_vt);
  // NSPLIT*NH*SEQ*HD == 3*XN exactly.
  float* Opart = (float*)alloc((size_t)NSPLIT * NH * SEQ * HD * 4);
  float* qraw = Opart;
  float* kraw = qraw + XN;
  float* vraw = kraw + XN;

  CastBatch cb;
  cb.src[0] = x;  cb.dst[0] = xb;  cb.n[0] = XN;
  cb.src[1] = Wq; cb.dst[1] = Wqb; cb.n[1] = WN;
  cb.src[2] = Wk; cb.dst[2] = Wkb; cb.n[2] = WN;
  cb.src[3] = Wv; cb.dst[3] = Wvb; cb.n[3] = WN;
  cb.src[4] = Wo; cb.dst[4] = Wob; cb.n[4] = WN;
  castall<<<dim3((XN + 2047) / 2048, 5), 256, 0, stream>>>(cb);

  clear_pad<<<dim3(((KVP - KV) * HD + 255) / 256, NH), 256, 0, stream>>>(Kcat, Vt);

  GemmBatch gqkv;
  gqkv.B[0] = Wqb; gqkv.B[1] = Wkb; gqkv.B[2] = Wvb;
  gqkv.bias[0] = bq; gqkv.bias[1] = bk; gqkv.bias[2] = bv;
  gqkv.C[0] = qraw; gqkv.C[1] = kraw; gqkv.C[2] = vraw;
  gemm_bt<<<dim3(13, 12, 3), 256, 0, stream>>>(xb, gqkv, SEQ);

  norm_rope<<<SEQ, 256, 0, stream>>>(qraw, kraw, nqw, nkw, fcos, fsin, QhB, Kcat);
  build_kcat<<<NEWBASE, 256, 0, stream>>>(cache_k, Kcat);
  build_vt<<<dim3(147, NH), 256, 0, stream>>>(cache_v, vraw, Vt);

  attn_split<<<dim3(NQT * NH * NSPLIT), 256, 0, stream>>>(QhB, Kcat, Vt, Opart, MLpart);
  attn_merge<<<(NH * SEQ + 1) / 2, 256, 0, stream>>>(Opart, MLpart, Aout);

  GemmBatch gout;
  gout.B[0] = Wob; gout.B[1] = Wob; gout.B[2] = Wob;
  gout.bias[0] = bo; gout.bias[1] = bo; gout.bias[2] = bo;
  gout.C[0] = out; gout.C[1] = out; gout.C[2] = out;
  gemm_bt<<<dim3(13, 12, 1), 256, 0, stream>>>(Aout, gout, SEQ);
}